// Round 1
// baseline (151.219 us; speedup 1.0000x reference)
//
#include <hip/hip_runtime.h>
#include <hip/hip_bf16.h>

// Haar DWT low/high frequency extractor.
// x: [B=4, C=64, H=512, W=512] fp32.
// Math: filters are an orthonormal basis of each 2x2 block, so
//   x_low[2h+p][2w+q] = 0.25*(block sum)   (LL-only synthesis)
//   x_high = x - x_low                      (LH+HL+HH synthesis = residual)
// Pure streaming, memory-bound: 256 MiB in, 512 MiB out.

#define HW_H 512
#define HW_W 512

__global__ __launch_bounds__(256) void
haar_lowhigh_kernel(const float* __restrict__ x,
                    float* __restrict__ lo,
                    float* __restrict__ hi,
                    int total_items) {
    // One item = a 2-row x 4-col patch (two adjacent 2x2 blocks).
    // items per plane: (H/2)*(W/4) = 256*128 = 32768
    const int stride = gridDim.x * blockDim.x;
    for (int i = blockIdx.x * blockDim.x + threadIdx.x; i < total_items; i += stride) {
        const int wq = i & 127;          // W/4 = 128 col-quads
        const int hr = (i >> 7) & 255;   // H/2 = 256 block-rows
        const int n  = i >> 15;          // plane index (B*C)
        const size_t base = (((size_t)n * HW_H) + 2 * hr) * HW_W + 4 * wq;

        const float4 r0 = *reinterpret_cast<const float4*>(x + base);
        const float4 r1 = *reinterpret_cast<const float4*>(x + base + HW_W);

        const float avg0 = 0.25f * ((r0.x + r0.y) + (r1.x + r1.y));
        const float avg1 = 0.25f * ((r0.z + r0.w) + (r1.z + r1.w));

        const float4 lo4 = make_float4(avg0, avg0, avg1, avg1);
        *reinterpret_cast<float4*>(lo + base)        = lo4;
        *reinterpret_cast<float4*>(lo + base + HW_W) = lo4;

        *reinterpret_cast<float4*>(hi + base) =
            make_float4(r0.x - avg0, r0.y - avg0, r0.z - avg1, r0.w - avg1);
        *reinterpret_cast<float4*>(hi + base + HW_W) =
            make_float4(r1.x - avg0, r1.y - avg0, r1.z - avg1, r1.w - avg1);
    }
}

extern "C" void kernel_launch(void* const* d_in, const int* in_sizes, int n_in,
                              void* d_out, int out_size, void* d_ws, size_t ws_size,
                              hipStream_t stream) {
    const float* x = (const float*)d_in[0];
    float* out = (float*)d_out;

    const size_t n_elems = (size_t)in_sizes[0];      // 4*64*512*512 = 67108864
    float* lo = out;                                  // x_low, flat
    float* hi = out + n_elems;                        // x_high, flat

    const int total_items = (int)(n_elems / 8);       // 8 elems per thread-item
    const int block = 256;
    const int grid = 4096;                            // grid-stride, ~32 waves/CU

    hipLaunchKernelGGL(haar_lowhigh_kernel, dim3(grid), dim3(block), 0, stream,
                       x, lo, hi, total_items);
}

// Round 3
// 143.276 us; speedup vs baseline: 1.0554x; 1.0554x over previous
//
#include <hip/hip_runtime.h>
#include <hip/hip_bf16.h>

// Haar DWT low/high frequency extractor.
// x: [B=4, C=64, H=512, W=512] fp32.
// Math: Haar filters are an orthonormal basis of each 2x2 block, so
//   x_low[2h+p][2w+q] = 0.25*(block sum)   (LL-only synthesis)
//   x_high = x - x_low                      (LH+HL+HH synthesis = residual)
// Pure streaming, memory-bound: 256 MiB in, 512 MiB out.
// Non-temporal loads/stores: zero reuse, skip L2 allocation.
// NOTE: nontemporal builtins need native clang vectors, not HIP_vector_type.

#define HW_H 512
#define HW_W 512

typedef float f32x4 __attribute__((ext_vector_type(4)));

__global__ __launch_bounds__(256) void
haar_lowhigh_kernel(const float* __restrict__ x,
                    float* __restrict__ lo,
                    float* __restrict__ hi,
                    int total_items) {
    // One item = a 2-row x 4-col patch (two adjacent 2x2 blocks).
    // items per plane: (H/2)*(W/4) = 256*128 = 32768
    const int stride = gridDim.x * blockDim.x;
    for (int i = blockIdx.x * blockDim.x + threadIdx.x; i < total_items; i += stride) {
        const int wq = i & 127;          // W/4 = 128 col-quads
        const int hr = (i >> 7) & 255;   // H/2 = 256 block-rows
        const int n  = i >> 15;          // plane index (B*C)
        const size_t base = (((size_t)n * HW_H) + 2 * hr) * HW_W + 4 * wq;

        const f32x4 r0 = __builtin_nontemporal_load(
            reinterpret_cast<const f32x4*>(x + base));
        const f32x4 r1 = __builtin_nontemporal_load(
            reinterpret_cast<const f32x4*>(x + base + HW_W));

        const float avg0 = 0.25f * ((r0.x + r0.y) + (r1.x + r1.y));
        const float avg1 = 0.25f * ((r0.z + r0.w) + (r1.z + r1.w));

        const f32x4 lo4 = {avg0, avg0, avg1, avg1};
        __builtin_nontemporal_store(lo4, reinterpret_cast<f32x4*>(lo + base));
        __builtin_nontemporal_store(lo4, reinterpret_cast<f32x4*>(lo + base + HW_W));

        const f32x4 hi0 = {r0.x - avg0, r0.y - avg0, r0.z - avg1, r0.w - avg1};
        const f32x4 hi1 = {r1.x - avg0, r1.y - avg0, r1.z - avg1, r1.w - avg1};
        __builtin_nontemporal_store(hi0, reinterpret_cast<f32x4*>(hi + base));
        __builtin_nontemporal_store(hi1, reinterpret_cast<f32x4*>(hi + base + HW_W));
    }
}

extern "C" void kernel_launch(void* const* d_in, const int* in_sizes, int n_in,
                              void* d_out, int out_size, void* d_ws, size_t ws_size,
                              hipStream_t stream) {
    const float* x = (const float*)d_in[0];
    float* out = (float*)d_out;

    const size_t n_elems = (size_t)in_sizes[0];      // 4*64*512*512 = 67108864
    float* lo = out;                                  // x_low, flat
    float* hi = out + n_elems;                        // x_high, flat

    const int total_items = (int)(n_elems / 8);       // 8 elems per thread-item
    const int block = 256;
    const int grid = 8192;                            // grid-stride, 4 iters/thread

    hipLaunchKernelGGL(haar_lowhigh_kernel, dim3(grid), dim3(block), 0, stream,
                       x, lo, hi, total_items);
}